// Round 11
// baseline (319.706 us; speedup 1.0000x reference)
//
#include <hip/hip_runtime.h>
#include <hip/hip_bf16.h>

#define N_NODE 50000
#define NEDGE  600000
#define NRANGE 128
#define RSZ    391       // ceil(N_NODE / NRANGE); 128*391 = 50048 >= 50000
#define CAPB   6144      // slot capacity per (rel,range): mean 4688 + ~21 sigma
#define CHUNK  8192
#define NBLK1  74        // ceil(NEDGE / CHUNK); last chunk = 1984 (divisible by 4)
#define GEMM_GB 49       // GEMM blocks per problem; each does 8 row-tiles of 128 (W staged once)

typedef __hip_bfloat16 bf16;
typedef __attribute__((ext_vector_type(8))) short short8;
typedef __attribute__((ext_vector_type(4))) float floatx4;

__device__ __forceinline__ short f2s(float f) {
    bf16 t = __float2bfloat16(f);
    return *(short*)&t;
}
__device__ __forceinline__ unsigned pk2(float lo, float hi) {
    return ((unsigned)(unsigned short)f2s(lo)) | (((unsigned)(unsigned short)f2s(hi)) << 16);
}
__device__ __forceinline__ void acc2(float& a, float& b, unsigned w, float m) {
    a += m * __uint_as_float(w << 16);
    b += m * __uint_as_float(w & 0xFFFF0000u);
}
// wave-inclusive scan (64 lanes), Kogge-Stone via shfl_up
__device__ __forceinline__ int wscan(int x, int lane) {
#pragma unroll
    for (int d = 1; d < 64; d <<= 1) {
        int t = __shfl_up(x, d);
        if (lane >= d) x += t;
    }
    return x;
}

// rel 0 = dd (dst=drug), 1 = gd (dst=drug), 2 = dg (dst=gene), 3 = gg (dst=gene)
// key packing: (bucket:7 << 25) | (dst_local:9 << 16) | (src:16)

// ---------- fused launch (512 thr): blocks [0,296) = edge partition, [296,394) = layer-1 GEMM ----------
// 394 blocks <= 1024 residency -> single scheduling round. GEMM path: W staged once, 8 row-tiles.
__global__ __launch_bounds__(512) void k_part_gemm(
    const int* __restrict__ d0, const int* __restrict__ s0,
    const int* __restrict__ d1, const int* __restrict__ s1,
    const int* __restrict__ d2, const int* __restrict__ s2,
    const int* __restrict__ d3, const int* __restrict__ s3,
    int* __restrict__ gcur, unsigned* __restrict__ gpart,
    const float* __restrict__ X0, const float* __restrict__ X1,
    const float* __restrict__ Wa0, const float* __restrict__ Wb0,
    const float* __restrict__ Wa1, const float* __restrict__ Wb1,
    bf16* __restrict__ out0, bf16* __restrict__ out1)
{
    __shared__ union {
        struct { unsigned buf[CHUNK]; int hcur[NRANGE]; int delta[NRANGE]; int wsum[2]; } p;
        short wl[4 * 8 * 512];   // 32 KB
    } u;

    int tid = threadIdx.x;
    if (blockIdx.x < 4 * NBLK1) {
        // ---------------- partition path (8192-edge chunks) ----------------
        int bid = blockIdx.x;
        int rel = bid / NBLK1;
        int c   = bid - rel * NBLK1;
        const int* dp = rel == 0 ? d0 : rel == 1 ? d1 : rel == 2 ? d2 : d3;
        const int* sp = rel == 0 ? s0 : rel == 1 ? s1 : rel == 2 ? s2 : s3;
        int e0 = c * CHUNK;
        int e1 = min(e0 + CHUNK, NEDGE);
        int cnt = e1 - e0;                 // 8192 or 1984; both divisible by 4
        const int4* dp4 = (const int4*)(dp + e0);
        const int4* sp4 = (const int4*)(sp + e0);
        int nv = cnt >> 2;

        if (tid < NRANGE) u.p.hcur[tid] = 0;
        __syncthreads();
        // pass 1: bucket counts (int4 loads, LDS atomics)
        for (int i = tid; i < nv; i += 512) {
            int4 d = dp4[i];
            atomicAdd(&u.p.hcur[d.x / RSZ], 1);
            atomicAdd(&u.p.hcur[d.y / RSZ], 1);
            atomicAdd(&u.p.hcur[d.z / RSZ], 1);
            atomicAdd(&u.p.hcur[d.w / RSZ], 1);
        }
        __syncthreads();
        // 128-wide exclusive scan via 2-wave shfl scan (1 barrier)
        int lane = tid & 63, wv6 = tid >> 6;
        int v = (tid < NRANGE) ? u.p.hcur[tid] : 0;
        int inc = wscan(v, lane);
        if (lane == 63 && wv6 < 2) u.p.wsum[wv6] = inc;
        __syncthreads();
        if (tid < NRANGE) {
            int incl  = inc + ((wv6 == 1) ? u.p.wsum[0] : 0);
            int start = incl - v;
            int bg    = rel * NRANGE + tid;
            int resv  = atomicAdd(&gcur[bg], v);
            u.p.delta[tid] = bg * CAPB + resv - start;
            u.p.hcur[tid]  = start;
        }
        __syncthreads();
        // pass 2: fill buf bucketed
        for (int i = tid; i < nv; i += 512) {
            int4 d = dp4[i];
            int4 s = sp4[i];
#define PUT(dd, ss) { int b = (dd) / RSZ; int p = atomicAdd(&u.p.hcur[b], 1); \
                      u.p.buf[p] = ((unsigned)b << 25) | ((unsigned)((dd) - b * RSZ) << 16) | (unsigned)(ss); }
            PUT(d.x, s.x) PUT(d.y, s.y) PUT(d.z, s.z) PUT(d.w, s.w)
#undef PUT
        }
        __syncthreads();
        // pass 3: scatter to global slots
        for (int i = tid * 4; i < cnt; i += 2048) {
            uint4 kb = *(const uint4*)&u.p.buf[i];
            gpart[u.p.delta[kb.x >> 25] + i + 0] = kb.x;
            gpart[u.p.delta[kb.y >> 25] + i + 1] = kb.y;
            gpart[u.p.delta[kb.z >> 25] + i + 2] = kb.z;
            gpart[u.p.delta[kb.w >> 25] + i + 3] = kb.w;
        }
    } else {
        // ---------------- layer-1 GEMM path: 8 row-tiles of 128 per block, W staged once ----------------
        constexpr int NB = 8, KC = 4, NH = 64;
        int bid2 = blockIdx.x - 4 * NBLK1;         // 0..97
        int sel  = bid2 >= GEMM_GB;
        int bx   = sel ? bid2 - GEMM_GB : bid2;
        const float* X  = sel ? X1 : X0;
        const float* Wa = sel ? Wa1 : Wa0;
        const float* Wb = sel ? Wb1 : Wb0;
        bf16*       outp = sel ? out1 : out0;

        for (int i = tid; i < KC * NB * 512; i += 512) {
            int j  = i & 7;
            int n  = (i >> 3) & 15;
            int q  = (i >> 7) & 3;
            int nb = (i >> 9) & (NB - 1);
            int kc = i >> 12;
            int k  = kc * 32 + q * 8 + j;
            int c  = nb * 16 + n;
            float w = (c < NH) ? Wa[k * NH + c] : Wb[k * NH + (c - NH)];
            u.wl[i] = f2s(w);
        }
        __syncthreads();

        int lane = tid & 63, wv = tid >> 6;        // wv in [0,8)
        int q = lane >> 4, lidx = lane & 15;

#pragma unroll 1
        for (int t = 0; t < 8; t++) {
            int tile = bx * 8 + t;
            if (tile * 128 >= N_NODE) break;       // dead tail tiles (bx=48, t=7)
            int row0 = tile * 128 + wv * 16;
            int rowA = min(row0 + lidx, N_NODE - 1);

            floatx4 acc[NB];
#pragma unroll
            for (int nb = 0; nb < NB; nb++) acc[nb] = (floatx4){0.f, 0.f, 0.f, 0.f};

#pragma unroll
            for (int kc = 0; kc < KC; kc++) {
                const float* Xf = X + (size_t)rowA * 128 + kc * 32 + q * 8;
                float4 f0 = *(const float4*)Xf;
                float4 f1 = *(const float4*)(Xf + 4);
                short8 a;
                a[0] = f2s(f0.x); a[1] = f2s(f0.y); a[2] = f2s(f0.z); a[3] = f2s(f0.w);
                a[4] = f2s(f1.x); a[5] = f2s(f1.y); a[6] = f2s(f1.z); a[7] = f2s(f1.w);
#pragma unroll
                for (int nb = 0; nb < NB; nb++) {
                    short8 b = *(const short8*)&u.wl[((kc * NB + nb) * 64 + lane) * 8];
                    acc[nb] = __builtin_amdgcn_mfma_f32_16x16x32_bf16(a, b, acc[nb], 0, 0, 0);
                }
            }
#pragma unroll
            for (int nb = 0; nb < NB; nb++) {
#pragma unroll
                for (int r = 0; r < 4; r++) {
                    int row = row0 + q * 4 + r;
                    if (row < N_NODE)
                        outp[(size_t)row * 128 + nb * 16 + lidx] = __float2bfloat16(acc[nb][r]);
                }
            }
        }
    }
}

// ---------- per (rel,range) block -> final CSR (512 thr, uint4 loads, shfl scans) ----------
__global__ __launch_bounds__(512) void k_csr(
    const unsigned* __restrict__ gpart, const int* __restrict__ gcnt,
    int* __restrict__ off, unsigned short* __restrict__ edges)
{
    __shared__ unsigned short stg[CAPB];   // first: 16B-aligned
    __shared__ int cur[RSZ];
    __shared__ int wsum[8];
    int bid = blockIdx.x;
    int rel = bid >> 7, r = bid & (NRANGE - 1);
    int tid = threadIdx.x;
    int lane = tid & 63, wv = tid >> 6;
    int range0 = r * RSZ;
    int RS = min(RSZ, N_NODE - range0);
    if (RS < 0) RS = 0;
    int count = gcnt[bid];
    const uint4* gp4 = (const uint4*)(gpart + (size_t)bid * CAPB);
    const unsigned* gp = gpart + (size_t)bid * CAPB;
    int count4 = count & ~3;

    // base = sum of gcnt[rel*128 + i] for i < r : masked 2-wave reduction (1 barrier)
    int vb = (tid < r) ? gcnt[rel * NRANGE + tid] : 0;   // tid<r implies tid<128
#pragma unroll
    for (int d = 32; d; d >>= 1) vb += __shfl_xor(vb, d);
    if (lane == 0 && wv < 2) wsum[wv] = vb;
    for (int i = tid; i < RSZ; i += 512) cur[i] = 0;
    __syncthreads();
    int base = wsum[0] + wsum[1];

    // hist (uint4)
    for (int i = tid * 4; i < count4; i += 2048) {
        uint4 g = gp4[i >> 2];
        atomicAdd(&cur[(g.x >> 16) & 0x1FF], 1);
        atomicAdd(&cur[(g.y >> 16) & 0x1FF], 1);
        atomicAdd(&cur[(g.z >> 16) & 0x1FF], 1);
        atomicAdd(&cur[(g.w >> 16) & 0x1FF], 1);
    }
    if (tid < (count & 3))
        atomicAdd(&cur[(gp[count4 + tid] >> 16) & 0x1FF], 1);
    __syncthreads();

    // 391-wide exclusive scan via 8-wave shfl scan (2 barriers)
    int x = (tid < RSZ) ? cur[tid] : 0;
    int inc = wscan(x, lane);
    if (lane == 63) wsum[wv] = inc;
    __syncthreads();
    int pre = 0;
#pragma unroll
    for (int w = 0; w < 7; w++) pre += (w < wv) ? wsum[w] : 0;
    int excl = inc + pre - x;
    if (tid < RSZ) cur[tid] = excl;
    __syncthreads();

    if (tid < RS)
        off[rel * (N_NODE + 1) + range0 + tid] = base + cur[tid];
    if (r == NRANGE - 1 && tid == 0) off[rel * (N_NODE + 1) + N_NODE] = NEDGE;
    // no barrier needed: off written from cur[tid] (own slot), scatter uses atomics on cur

    // scatter to stg (uint4)
    for (int i = tid * 4; i < count4; i += 2048) {
        uint4 g = gp4[i >> 2];
#define SCAT(gg) { int p = atomicAdd(&cur[((gg) >> 16) & 0x1FF], 1); stg[p] = (unsigned short)((gg) & 0xFFFFu); }
        SCAT(g.x) SCAT(g.y) SCAT(g.z) SCAT(g.w)
#undef SCAT
    }
    if (tid < (count & 3)) {
        unsigned g = gp[count4 + tid];
        int p = atomicAdd(&cur[(g >> 16) & 0x1FF], 1);
        stg[p] = (unsigned short)(g & 0xFFFFu);
    }
    __syncthreads();
    for (int i = tid; i < count; i += 512)
        edges[(size_t)rel * NEDGE + base + i] = stg[i];
}

// ---------- MFMA dual-weight GEMM pair (layer 2): out(bf16) = X @ [Wa | Wb] ----------
template <int K, int NOUT, bool AFP32>
__global__ __launch_bounds__(256) void k_gemm_pair(
    const void* __restrict__ X0, const void* __restrict__ X1,
    const float* __restrict__ Wa0, const float* __restrict__ Wb0,
    const float* __restrict__ Wa1, const float* __restrict__ Wb1,
    bf16* __restrict__ out0, bf16* __restrict__ out1, int M)
{
    constexpr int NB  = NOUT / 16;
    constexpr int KC  = K / 32;
    constexpr int NH  = NOUT / 2;
    constexpr int NBL = (NB == 8) ? 3 : 2;
    __shared__ short Wl[KC * NB * 512];

    int sel = blockIdx.y;
    const void*  X  = sel ? X1 : X0;
    const float* Wa = sel ? Wa1 : Wa0;
    const float* Wb = sel ? Wb1 : Wb0;
    bf16*        out = sel ? out1 : out0;

    int tid = threadIdx.x;
    for (int i = tid; i < KC * NB * 512; i += 256) {
        int j  = i & 7;
        int n  = (i >> 3) & 15;
        int q  = (i >> 7) & 3;
        int nb = (i >> 9) & (NB - 1);
        int kc = i >> (9 + NBL);
        int k  = kc * 32 + q * 8 + j;
        int c  = nb * 16 + n;
        float w = (c < NH) ? Wa[k * NH + c] : Wb[k * NH + (c - NH)];
        Wl[i] = f2s(w);
    }
    __syncthreads();

    int lane = tid & 63, wv = tid >> 6;
    int q = lane >> 4, lidx = lane & 15;
    int row0 = blockIdx.x * 64 + wv * 16;
    int rowA = min(row0 + lidx, M - 1);

    floatx4 acc[NB];
#pragma unroll
    for (int nb = 0; nb < NB; nb++) acc[nb] = (floatx4){0.f, 0.f, 0.f, 0.f};

#pragma unroll
    for (int kc = 0; kc < KC; kc++) {
        short8 a;
        if constexpr (AFP32) {
            const float* Xf = (const float*)X + (size_t)rowA * K + kc * 32 + q * 8;
            float4 f0 = *(const float4*)Xf;
            float4 f1 = *(const float4*)(Xf + 4);
            a[0] = f2s(f0.x); a[1] = f2s(f0.y); a[2] = f2s(f0.z); a[3] = f2s(f0.w);
            a[4] = f2s(f1.x); a[5] = f2s(f1.y); a[6] = f2s(f1.z); a[7] = f2s(f1.w);
        } else {
            a = *(const short8*)((const short*)X + (size_t)rowA * K + kc * 32 + q * 8);
        }
#pragma unroll
        for (int nb = 0; nb < NB; nb++) {
            short8 b = *(const short8*)&Wl[((kc * NB + nb) * 64 + lane) * 8];
            acc[nb] = __builtin_amdgcn_mfma_f32_16x16x32_bf16(a, b, acc[nb], 0, 0, 0);
        }
    }
#pragma unroll
    for (int nb = 0; nb < NB; nb++) {
#pragma unroll
        for (int r = 0; r < 4; r++) {
            int row = row0 + q * 4 + r;
            if (row < M)
                out[(size_t)row * NOUT + nb * 16 + lidx] = __float2bfloat16(acc[nb][r]);
        }
    }
}

// ---------- group-per-node segment accumulate (round-2 proven structure, u16 edges) ----------
template<int ROWU>
__device__ __forceinline__ void seg_run(
    int n, const unsigned short* __restrict__ ep, float sc,
    const unsigned* __restrict__ base, float* s)
{
    int nfull = n & ~3;
    for (int i = 0; i < nfull; i += 4) {
        int e0 = ep[i + 0];
        int e1 = ep[i + 1];
        int e2 = ep[i + 2];
        int e3 = ep[i + 3];
        uint4 w0 = *(const uint4*)(base + e0 * ROWU);
        uint4 w1 = *(const uint4*)(base + e1 * ROWU);
        uint4 w2 = *(const uint4*)(base + e2 * ROWU);
        uint4 w3 = *(const uint4*)(base + e3 * ROWU);
        acc2(s[0], s[1], w0.x, sc); acc2(s[2], s[3], w0.y, sc);
        acc2(s[4], s[5], w0.z, sc); acc2(s[6], s[7], w0.w, sc);
        acc2(s[0], s[1], w1.x, sc); acc2(s[2], s[3], w1.y, sc);
        acc2(s[4], s[5], w1.z, sc); acc2(s[6], s[7], w1.w, sc);
        acc2(s[0], s[1], w2.x, sc); acc2(s[2], s[3], w2.y, sc);
        acc2(s[4], s[5], w2.z, sc); acc2(s[6], s[7], w2.w, sc);
        acc2(s[0], s[1], w3.x, sc); acc2(s[2], s[3], w3.y, sc);
        acc2(s[4], s[5], w3.z, sc); acc2(s[6], s[7], w3.w, sc);
    }
    for (int i = nfull; i < n; i++) {
        int e = ep[i];
        uint4 w = *(const uint4*)(base + e * ROWU);
        acc2(s[0], s[1], w.x, sc); acc2(s[2], s[3], w.y, sc);
        acc2(s[4], s[5], w.z, sc); acc2(s[6], s[7], w.w, sc);
    }
}

// ---------- fused layer-1 gather: 8-lane group per node, 64 feats ----------
__global__ __launch_bounds__(256) void k_gather64v5(
    const bf16* __restrict__ m1,
    const int* __restrict__ offA0, const unsigned short* __restrict__ eA0,
    const int* __restrict__ offB0, const unsigned short* __restrict__ eB0,
    const float* __restrict__ bias0, bf16* __restrict__ out0,
    const int* __restrict__ offA1, const unsigned short* __restrict__ eA1,
    const int* __restrict__ offB1, const unsigned short* __restrict__ eB1,
    const float* __restrict__ bias1, bf16* __restrict__ out1)
{
    int tid  = threadIdx.x;
    int gid  = blockIdx.x * 32 + (tid >> 3);   // grid exact: 3125*32 = 100000
    int lidx = tid & 7;
    int half = (gid >= N_NODE);
    int wid  = gid - (half ? N_NODE : 0);
    const int* offA = half ? offA1 : offA0;
    const unsigned short* eA = half ? eA1 : eA0;
    const int* offB = half ? offB1 : offB0;
    const unsigned short* eB = half ? eB1 : eB0;
    const float* bias = half ? bias1 : bias0;
    bf16* out = half ? out1 : out0;

    const unsigned* base = (const unsigned*)m1 + (half ? 32 : 0) + lidx * 4;

    int begA = offA[wid], nA = offA[wid + 1] - begA;
    int begB = offB[wid], nB = offB[wid + 1] - begB;
    float ia = 1.f / (float)max(nA, 1);
    float ib = 1.f / (float)max(nB, 1);

    float s[8] = {0.f,0.f,0.f,0.f,0.f,0.f,0.f,0.f};
    seg_run<64>(nA, eA + begA, ia, base, s);
    seg_run<64>(nB, eB + begB, ib, base + N_NODE * 64, s);

    float h[8];
#pragma unroll
    for (int k = 0; k < 8; k++)
        h[k] = fmaxf(s[k] + bias[lidx * 8 + k], 0.f);
    uint4 v;
    v.x = pk2(h[0], h[1]); v.y = pk2(h[2], h[3]);
    v.z = pk2(h[4], h[5]); v.w = pk2(h[6], h[7]);
    *(uint4*)(out + (size_t)wid * 64 + lidx * 8) = v;
}

// ---------- fused layer-2 gather: 4-lane group per node, 32 feats, f32 out ----------
__global__ __launch_bounds__(256) void k_gather32v2(
    const bf16* __restrict__ m2,
    const int* __restrict__ offA0, const unsigned short* __restrict__ eA0,
    const int* __restrict__ offB0, const unsigned short* __restrict__ eB0,
    const float* __restrict__ bias0, float* __restrict__ out0,
    const int* __restrict__ offA1, const unsigned short* __restrict__ eA1,
    const int* __restrict__ offB1, const unsigned short* __restrict__ eB1,
    const float* __restrict__ bias1, float* __restrict__ out1)
{
    int tid  = threadIdx.x;
    int gid  = blockIdx.x * 64 + (tid >> 2);
    int lidx = tid & 3;
    if (gid >= 2 * N_NODE) return;
    int half = (gid >= N_NODE);
    int wid  = gid - (half ? N_NODE : 0);
    const int* offA = half ? offA1 : offA0;
    const unsigned short* eA = half ? eA1 : eA0;
    const int* offB = half ? offB1 : offB0;
    const unsigned short* eB = half ? eB1 : eB0;
    const float* bias = half ? bias1 : bias0;
    float* out = half ? out1 : out0;

    const unsigned* base = (const unsigned*)m2 + (half ? 16 : 0) + lidx * 4;

    int begA = offA[wid], nA = offA[wid + 1] - begA;
    int begB = offB[wid], nB = offB[wid + 1] - begB;
    float ia = 1.f / (float)max(nA, 1);
    float ib = 1.f / (float)max(nB, 1);

    float s[8] = {0.f,0.f,0.f,0.f,0.f,0.f,0.f,0.f};
    seg_run<32>(nA, eA + begA, ia, base, s);
    seg_run<32>(nB, eB + begB, ib, base + N_NODE * 32, s);

    float* o = out + (size_t)wid * 32 + lidx * 8;
    float4 v0, v1;
    v0.x = s[0] + bias[lidx * 8 + 0];
    v0.y = s[1] + bias[lidx * 8 + 1];
    v0.z = s[2] + bias[lidx * 8 + 2];
    v0.w = s[3] + bias[lidx * 8 + 3];
    v1.x = s[4] + bias[lidx * 8 + 4];
    v1.y = s[5] + bias[lidx * 8 + 5];
    v1.z = s[6] + bias[lidx * 8 + 6];
    v1.w = s[7] + bias[lidx * 8 + 7];
    *(float4*)o = v0;
    *(float4*)(o + 4) = v1;
}

// ---------------- launcher ----------------
extern "C" void kernel_launch(void* const* d_in, const int* in_sizes, int n_in,
                              void* d_out, int out_size, void* d_ws, size_t ws_size,
                              hipStream_t stream)
{
    const float* xd = (const float*)d_in[0];
    const float* xg = (const float*)d_in[1];
    const int* dd_src = (const int*)d_in[2];  const int* dd_dst = (const int*)d_in[3];
    const int* dg_src = (const int*)d_in[4];  const int* dg_dst = (const int*)d_in[5];
    const int* gd_src = (const int*)d_in[6];  const int* gd_dst = (const int*)d_in[7];
    const int* gg_src = (const int*)d_in[8];  const int* gg_dst = (const int*)d_in[9];
    const float* W1dd = (const float*)d_in[10];
    const float* W1dg = (const float*)d_in[11];
    const float* W1gd = (const float*)d_in[12];
    const float* W1gg = (const float*)d_in[13];
    const float* b1d  = (const float*)d_in[14];
    const float* b1g  = (const float*)d_in[15];
    const float* W2dd = (const float*)d_in[16];
    const float* W2dg = (const float*)d_in[17];
    const float* W2gd = (const float*)d_in[18];
    const float* W2gg = (const float*)d_in[19];
    const float* b2d  = (const float*)d_in[20];
    const float* b2g  = (const float*)d_in[21];
    float* out = (float*)d_out;

    // workspace layout (vector-accessed regions 16B-aligned)
    int* gcur     = (int*)d_ws;                        // 512 ints
    int* off      = gcur + 512;                        // 4*(N_NODE+1) = 200004
    unsigned short* edges = (unsigned short*)(off + 4 * (N_NODE + 1));  // 4*NEDGE u16 (4.8 MB)
    bf16* md1     = (bf16*)(edges + (size_t)4 * NEDGE);// [md1|mg1]: 2*50000*128 bf16 (25.6 MB)
    bf16* mg1     = md1 + (size_t)N_NODE * 128;
    bf16* h       = mg1 + (size_t)N_NODE * 128;        // [hd|hg]: 2*50000*64 bf16 (12.8 MB)
    bf16* hd      = h;
    bf16* hg      = h + (size_t)N_NODE * 64;
    bf16* md2     = md1;                               // layer-2 out packed (stride 64 bf16)
    bf16* mg2     = md1 + (size_t)N_NODE * 64;         // B-row i = row (i + N_NODE)
    unsigned* gpart = (unsigned*)h;                    // 512*CAPB uints (12.58 MB) aliases h:
                                                       // dead after k_csr, before gather64 writes h.
                                                       // (md1 must NOT alias gpart: GEMM runs || part.)

    // ---- stage 1: edge partition || layer-1 GEMM (394 blocks -> single scheduling round) ----
    hipMemsetAsync(gcur, 0, 512 * sizeof(int), stream);
    k_part_gemm<<<4 * NBLK1 + 2 * GEMM_GB, 512, 0, stream>>>(
        dd_dst, dd_src, gd_dst, gd_src, dg_dst, dg_src, gg_dst, gg_src, gcur, gpart,
        xd, xg, W1dd, W1dg, W1gd, W1gg, md1, mg1);

    // ---- stage 2: CSR finalize ----
    k_csr<<<512, 512, 0, stream>>>(gpart, gcur, off, edges);

    const int* off_dd = off + 0 * (N_NODE + 1);
    const int* off_gd = off + 1 * (N_NODE + 1);
    const int* off_dg = off + 2 * (N_NODE + 1);
    const int* off_gg = off + 3 * (N_NODE + 1);
    const unsigned short* e_dd = edges + (size_t)0 * NEDGE;
    const unsigned short* e_gd = edges + (size_t)1 * NEDGE;
    const unsigned short* e_dg = edges + (size_t)2 * NEDGE;
    const unsigned short* e_gg = edges + (size_t)3 * NEDGE;

    int g64_grid = (2 * N_NODE) / 32;          // 3125 blocks exact
    int g32_grid = (2 * N_NODE + 63) / 64;     // 1563 blocks
    dim3 gemm2_grid((N_NODE + 63) / 64, 2);

    // ---- stage 3: layer-1 gather -> h ----
    k_gather64v5<<<g64_grid, 256, 0, stream>>>(
        md1,
        off_dd, e_dd, off_gd, e_gd, b1d, hd,
        off_dg, e_dg, off_gg, e_gg, b1g, hg);

    // ---- stage 4: layer-2 GEMM (md1 region is dead now) ----
    k_gemm_pair<64, 64, false><<<gemm2_grid, 256, 0, stream>>>(
        hd, hg, W2dd, W2dg, W2gd, W2gg, md2, mg2, N_NODE);

    // ---- stage 5: layer-2 gather -> out ----
    k_gather32v2<<<g32_grid, 256, 0, stream>>>(
        md2,
        off_dd, e_dd, off_gd, e_gd, b2d, out,
        off_dg, e_dg, off_gg, e_gg, b2g, out + (size_t)N_NODE * 32);
}

// Round 12
// 304.506 us; speedup vs baseline: 1.0499x; 1.0499x over previous
//
#include <hip/hip_runtime.h>
#include <hip/hip_bf16.h>

#define N_NODE 50000
#define NEDGE  600000
#define NRANGE 128
#define RSZ    391       // ceil(N_NODE / NRANGE); 128*391 = 50048 >= 50000
#define CAPB   6144      // slot capacity per (rel,range): mean 4688 + ~21 sigma
#define CHUNK  4096      // standalone-part chunk; 588 blocks for solo occupancy
#define NBLK1  147       // ceil(NEDGE / CHUNK); last chunk = 1984 (divisible by 4)
#define GEMM_GB 196      // GEMM blocks per problem; each does 2 row-tiles of 128 (r10 proven)
#define NCSR   512       // csr blocks in fused launch

typedef __hip_bfloat16 bf16;
typedef __attribute__((ext_vector_type(8))) short short8;
typedef __attribute__((ext_vector_type(4))) float floatx4;

__device__ __forceinline__ short f2s(float f) {
    bf16 t = __float2bfloat16(f);
    return *(short*)&t;
}
__device__ __forceinline__ unsigned pk2(float lo, float hi) {
    return ((unsigned)(unsigned short)f2s(lo)) | (((unsigned)(unsigned short)f2s(hi)) << 16);
}
__device__ __forceinline__ void acc2(float& a, float& b, unsigned w, float m) {
    a += m * __uint_as_float(w << 16);
    b += m * __uint_as_float(w & 0xFFFF0000u);
}
// wave-inclusive scan (64 lanes), Kogge-Stone via shfl_up
__device__ __forceinline__ int wscan(int x, int lane) {
#pragma unroll
    for (int d = 1; d < 64; d <<= 1) {
        int t = __shfl_up(x, d);
        if (lane >= d) x += t;
    }
    return x;
}

// rel 0 = dd (dst=drug), 1 = gd (dst=drug), 2 = dg (dst=gene), 3 = gg (dst=gene)
// key packing: (bucket:7 << 25) | (dst_local:9 << 16) | (src:16)

// ---------- stage 1: standalone edge partition (588 blocks, 512 thr, shfl scan) ----------
__global__ __launch_bounds__(512) void k_part(
    const int* __restrict__ d0, const int* __restrict__ s0,
    const int* __restrict__ d1, const int* __restrict__ s1,
    const int* __restrict__ d2, const int* __restrict__ s2,
    const int* __restrict__ d3, const int* __restrict__ s3,
    int* __restrict__ gcur, unsigned* __restrict__ gpart)
{
    __shared__ unsigned buf[CHUNK];
    __shared__ int hcur[NRANGE];
    __shared__ int delta[NRANGE];
    __shared__ int wsum2[2];

    int tid = threadIdx.x;
    int bid = blockIdx.x;
    int rel = bid / NBLK1;
    int c   = bid - rel * NBLK1;
    const int* dp = rel == 0 ? d0 : rel == 1 ? d1 : rel == 2 ? d2 : d3;
    const int* sp = rel == 0 ? s0 : rel == 1 ? s1 : rel == 2 ? s2 : s3;
    int e0 = c * CHUNK;
    int e1 = min(e0 + CHUNK, NEDGE);
    int cnt = e1 - e0;                 // 4096 or 1984; both divisible by 4
    const int4* dp4 = (const int4*)(dp + e0);
    const int4* sp4 = (const int4*)(sp + e0);
    int nv = cnt >> 2;

    if (tid < NRANGE) hcur[tid] = 0;
    __syncthreads();
    // pass 1: bucket counts (int4 loads, LDS atomics)
    for (int i = tid; i < nv; i += 512) {
        int4 d = dp4[i];
        atomicAdd(&hcur[d.x / RSZ], 1);
        atomicAdd(&hcur[d.y / RSZ], 1);
        atomicAdd(&hcur[d.z / RSZ], 1);
        atomicAdd(&hcur[d.w / RSZ], 1);
    }
    __syncthreads();
    // 128-wide exclusive scan via 2-wave shfl scan (1 barrier)
    int lane = tid & 63, wv6 = tid >> 6;
    int v = (tid < NRANGE) ? hcur[tid] : 0;
    int inc = wscan(v, lane);
    if (lane == 63 && wv6 < 2) wsum2[wv6] = inc;
    __syncthreads();
    if (tid < NRANGE) {
        int incl  = inc + ((wv6 == 1) ? wsum2[0] : 0);
        int start = incl - v;
        int bg    = rel * NRANGE + tid;
        int resv  = atomicAdd(&gcur[bg], v);
        delta[tid] = bg * CAPB + resv - start;
        hcur[tid]  = start;
    }
    __syncthreads();
    // pass 2: fill buf bucketed
    for (int i = tid; i < nv; i += 512) {
        int4 d = dp4[i];
        int4 s = sp4[i];
#define PUT(dd, ss) { int b = (dd) / RSZ; int p = atomicAdd(&hcur[b], 1); \
                      buf[p] = ((unsigned)b << 25) | ((unsigned)((dd) - b * RSZ) << 16) | (unsigned)(ss); }
        PUT(d.x, s.x) PUT(d.y, s.y) PUT(d.z, s.z) PUT(d.w, s.w)
#undef PUT
    }
    __syncthreads();
    // pass 3: scatter to global slots
    for (int i = tid * 4; i < cnt; i += 2048) {
        uint4 kb = *(const uint4*)&buf[i];
        gpart[delta[kb.x >> 25] + i + 0] = kb.x;
        gpart[delta[kb.y >> 25] + i + 1] = kb.y;
        gpart[delta[kb.z >> 25] + i + 2] = kb.z;
        gpart[delta[kb.w >> 25] + i + 3] = kb.w;
    }
}

// ---------- stage 2 fused: blocks [0,512) = CSR finalize, [512,904) = layer-1 GEMM ----------
// csr (reads gpart/gcur from k_part) and gemm1 (reads x/W1, writes md1) are independent;
// co-scheduling hides gemm1 under the csr critical path instead of running csr serial.
__global__ __launch_bounds__(512) void k_csr_gemm(
    const unsigned* __restrict__ gpart, const int* __restrict__ gcnt,
    int* __restrict__ off, unsigned short* __restrict__ edges,
    const float* __restrict__ X0, const float* __restrict__ X1,
    const float* __restrict__ Wa0, const float* __restrict__ Wb0,
    const float* __restrict__ Wa1, const float* __restrict__ Wb1,
    bf16* __restrict__ out0, bf16* __restrict__ out1)
{
    __shared__ union {
        struct { unsigned short stg[CAPB]; int cur[RSZ]; int wsum[8]; } c;   // ~14 KB
        short wl[4 * 8 * 512];                                               // 32 KB
    } u;

    int tid = threadIdx.x;
    if (blockIdx.x < NCSR) {
        // ---------------- CSR path (r10 proven form) ----------------
        int bid = blockIdx.x;
        int rel = bid >> 7, r = bid & (NRANGE - 1);
        int lane = tid & 63, wv = tid >> 6;
        int range0 = r * RSZ;
        int RS = min(RSZ, N_NODE - range0);
        if (RS < 0) RS = 0;
        int count = gcnt[bid];
        const uint4* gp4 = (const uint4*)(gpart + (size_t)bid * CAPB);
        const unsigned* gp = gpart + (size_t)bid * CAPB;
        int count4 = count & ~3;

        // base = sum of gcnt[rel*128 + i] for i < r : masked 2-wave reduction (1 barrier)
        int vb = (tid < r) ? gcnt[rel * NRANGE + tid] : 0;   // tid<r implies tid<128
#pragma unroll
        for (int d = 32; d; d >>= 1) vb += __shfl_xor(vb, d);
        if (lane == 0 && wv < 2) u.c.wsum[wv] = vb;
        for (int i = tid; i < RSZ; i += 512) u.c.cur[i] = 0;
        __syncthreads();
        int base = u.c.wsum[0] + u.c.wsum[1];

        // hist (uint4)
        for (int i = tid * 4; i < count4; i += 2048) {
            uint4 g = gp4[i >> 2];
            atomicAdd(&u.c.cur[(g.x >> 16) & 0x1FF], 1);
            atomicAdd(&u.c.cur[(g.y >> 16) & 0x1FF], 1);
            atomicAdd(&u.c.cur[(g.z >> 16) & 0x1FF], 1);
            atomicAdd(&u.c.cur[(g.w >> 16) & 0x1FF], 1);
        }
        if (tid < (count & 3))
            atomicAdd(&u.c.cur[(gp[count4 + tid] >> 16) & 0x1FF], 1);
        __syncthreads();

        // 391-wide exclusive scan via 8-wave shfl scan (2 barriers)
        int x = (tid < RSZ) ? u.c.cur[tid] : 0;
        int inc = wscan(x, lane);
        if (lane == 63) u.c.wsum[wv] = inc;
        __syncthreads();
        int pre = 0;
#pragma unroll
        for (int w = 0; w < 7; w++) pre += (w < wv) ? u.c.wsum[w] : 0;
        int excl = inc + pre - x;
        if (tid < RSZ) u.c.cur[tid] = excl;
        __syncthreads();

        if (tid < RS)
            off[rel * (N_NODE + 1) + range0 + tid] = base + u.c.cur[tid];
        if (r == NRANGE - 1 && tid == 0) off[rel * (N_NODE + 1) + N_NODE] = NEDGE;
        // no barrier needed: off written from cur[tid] (own slot), scatter uses atomics on cur

        // scatter to stg (uint4)
        for (int i = tid * 4; i < count4; i += 2048) {
            uint4 g = gp4[i >> 2];
#define SCAT(gg) { int p = atomicAdd(&u.c.cur[((gg) >> 16) & 0x1FF], 1); \
                   u.c.stg[p] = (unsigned short)((gg) & 0xFFFFu); }
            SCAT(g.x) SCAT(g.y) SCAT(g.z) SCAT(g.w)
#undef SCAT
        }
        if (tid < (count & 3)) {
            unsigned g = gp[count4 + tid];
            int p = atomicAdd(&u.c.cur[(g >> 16) & 0x1FF], 1);
            u.c.stg[p] = (unsigned short)(g & 0xFFFFu);
        }
        __syncthreads();
        for (int i = tid; i < count; i += 512)
            edges[(size_t)rel * NEDGE + base + i] = u.c.stg[i];
    } else {
        // ---------------- layer-1 GEMM path: 2 row-tiles of 128 per block, 8 waves (r10 proven) ----------------
        constexpr int NB = 8, KC = 4, NH = 64;
        int bid2 = blockIdx.x - NCSR;              // 0..391
        int sel  = bid2 >= GEMM_GB;
        int bx   = sel ? bid2 - GEMM_GB : bid2;
        const float* X  = sel ? X1 : X0;
        const float* Wa = sel ? Wa1 : Wa0;
        const float* Wb = sel ? Wb1 : Wb0;
        bf16*       outp = sel ? out1 : out0;

        for (int i = tid; i < KC * NB * 512; i += 512) {
            int j  = i & 7;
            int n  = (i >> 3) & 15;
            int q  = (i >> 7) & 3;
            int nb = (i >> 9) & (NB - 1);
            int kc = i >> 12;
            int k  = kc * 32 + q * 8 + j;
            int c  = nb * 16 + n;
            float w = (c < NH) ? Wa[k * NH + c] : Wb[k * NH + (c - NH)];
            u.wl[i] = f2s(w);
        }
        __syncthreads();

        int lane = tid & 63, wv = tid >> 6;        // wv in [0,8)
        int q = lane >> 4, lidx = lane & 15;

#pragma unroll
        for (int t = 0; t < 2; t++) {
            int tile = bx * 2 + t;
            if (tile * 128 >= N_NODE) break;       // dead tail tile (tile 391)
            int row0 = tile * 128 + wv * 16;
            int rowA = min(row0 + lidx, N_NODE - 1);

            floatx4 acc[NB];
#pragma unroll
            for (int nb = 0; nb < NB; nb++) acc[nb] = (floatx4){0.f, 0.f, 0.f, 0.f};

#pragma unroll
            for (int kc = 0; kc < KC; kc++) {
                const float* Xf = X + (size_t)rowA * 128 + kc * 32 + q * 8;
                float4 f0 = *(const float4*)Xf;
                float4 f1 = *(const float4*)(Xf + 4);
                short8 a;
                a[0] = f2s(f0.x); a[1] = f2s(f0.y); a[2] = f2s(f0.z); a[3] = f2s(f0.w);
                a[4] = f2s(f1.x); a[5] = f2s(f1.y); a[6] = f2s(f1.z); a[7] = f2s(f1.w);
#pragma unroll
                for (int nb = 0; nb < NB; nb++) {
                    short8 b = *(const short8*)&u.wl[((kc * NB + nb) * 64 + lane) * 8];
                    acc[nb] = __builtin_amdgcn_mfma_f32_16x16x32_bf16(a, b, acc[nb], 0, 0, 0);
                }
            }
#pragma unroll
            for (int nb = 0; nb < NB; nb++) {
#pragma unroll
                for (int r = 0; r < 4; r++) {
                    int row = row0 + q * 4 + r;
                    if (row < N_NODE)
                        outp[(size_t)row * 128 + nb * 16 + lidx] = __float2bfloat16(acc[nb][r]);
                }
            }
        }
    }
}

// ---------- MFMA dual-weight GEMM pair (layer 2): out(bf16) = X @ [Wa | Wb] ----------
template <int K, int NOUT, bool AFP32>
__global__ __launch_bounds__(256) void k_gemm_pair(
    const void* __restrict__ X0, const void* __restrict__ X1,
    const float* __restrict__ Wa0, const float* __restrict__ Wb0,
    const float* __restrict__ Wa1, const float* __restrict__ Wb1,
    bf16* __restrict__ out0, bf16* __restrict__ out1, int M)
{
    constexpr int NB  = NOUT / 16;
    constexpr int KC  = K / 32;
    constexpr int NH  = NOUT / 2;
    constexpr int NBL = (NB == 8) ? 3 : 2;
    __shared__ short Wl[KC * NB * 512];

    int sel = blockIdx.y;
    const void*  X  = sel ? X1 : X0;
    const float* Wa = sel ? Wa1 : Wa0;
    const float* Wb = sel ? Wb1 : Wb0;
    bf16*        out = sel ? out1 : out0;

    int tid = threadIdx.x;
    for (int i = tid; i < KC * NB * 512; i += 256) {
        int j  = i & 7;
        int n  = (i >> 3) & 15;
        int q  = (i >> 7) & 3;
        int nb = (i >> 9) & (NB - 1);
        int kc = i >> (9 + NBL);
        int k  = kc * 32 + q * 8 + j;
        int c  = nb * 16 + n;
        float w = (c < NH) ? Wa[k * NH + c] : Wb[k * NH + (c - NH)];
        Wl[i] = f2s(w);
    }
    __syncthreads();

    int lane = tid & 63, wv = tid >> 6;
    int q = lane >> 4, lidx = lane & 15;
    int row0 = blockIdx.x * 64 + wv * 16;
    int rowA = min(row0 + lidx, M - 1);

    floatx4 acc[NB];
#pragma unroll
    for (int nb = 0; nb < NB; nb++) acc[nb] = (floatx4){0.f, 0.f, 0.f, 0.f};

#pragma unroll
    for (int kc = 0; kc < KC; kc++) {
        short8 a;
        if constexpr (AFP32) {
            const float* Xf = (const float*)X + (size_t)rowA * K + kc * 32 + q * 8;
            float4 f0 = *(const float4*)Xf;
            float4 f1 = *(const float4*)(Xf + 4);
            a[0] = f2s(f0.x); a[1] = f2s(f0.y); a[2] = f2s(f0.z); a[3] = f2s(f0.w);
            a[4] = f2s(f1.x); a[5] = f2s(f1.y); a[6] = f2s(f1.z); a[7] = f2s(f1.w);
        } else {
            a = *(const short8*)((const short*)X + (size_t)rowA * K + kc * 32 + q * 8);
        }
#pragma unroll
        for (int nb = 0; nb < NB; nb++) {
            short8 b = *(const short8*)&Wl[((kc * NB + nb) * 64 + lane) * 8];
            acc[nb] = __builtin_amdgcn_mfma_f32_16x16x32_bf16(a, b, acc[nb], 0, 0, 0);
        }
    }
#pragma unroll
    for (int nb = 0; nb < NB; nb++) {
#pragma unroll
        for (int r = 0; r < 4; r++) {
            int row = row0 + q * 4 + r;
            if (row < M)
                out[(size_t)row * NOUT + nb * 16 + lidx] = __float2bfloat16(acc[nb][r]);
        }
    }
}

// ---------- group-per-node segment accumulate (round-2 proven structure, u16 edges) ----------
template<int ROWU>
__device__ __forceinline__ void seg_run(
    int n, const unsigned short* __restrict__ ep, float sc,
    const unsigned* __restrict__ base, float* s)
{
    int nfull = n & ~3;
    for (int i = 0; i < nfull; i += 4) {
        int e0 = ep[i + 0];
        int e1 = ep[i + 1];
        int e2 = ep[i + 2];
        int e3 = ep[i + 3];
        uint4 w0 = *(const uint4*)(base + e0 * ROWU);
        uint4 w1 = *(const uint4*)(base + e1 * ROWU);
        uint4 w2 = *(const uint4*)(base + e2 * ROWU);
        uint4 w3 = *(const uint4*)(base + e3 * ROWU);
        acc2(s[0], s[1], w0.x, sc); acc2(s[2], s[3], w0.y, sc);
        acc2(s[4], s[5], w0.z, sc); acc2(s[6], s[7], w0.w, sc);
        acc2(s[0], s[1], w1.x, sc); acc2(s[2], s[3], w1.y, sc);
        acc2(s[4], s[5], w1.z, sc); acc2(s[6], s[7], w1.w, sc);
        acc2(s[0], s[1], w2.x, sc); acc2(s[2], s[3], w2.y, sc);
        acc2(s[4], s[5], w2.z, sc); acc2(s[6], s[7], w2.w, sc);
        acc2(s[0], s[1], w3.x, sc); acc2(s[2], s[3], w3.y, sc);
        acc2(s[4], s[5], w3.z, sc); acc2(s[6], s[7], w3.w, sc);
    }
    for (int i = nfull; i < n; i++) {
        int e = ep[i];
        uint4 w = *(const uint4*)(base + e * ROWU);
        acc2(s[0], s[1], w.x, sc); acc2(s[2], s[3], w.y, sc);
        acc2(s[4], s[5], w.z, sc); acc2(s[6], s[7], w.w, sc);
    }
}

// ---------- fused layer-1 gather: 8-lane group per node, 64 feats ----------
__global__ __launch_bounds__(256) void k_gather64v5(
    const bf16* __restrict__ m1,
    const int* __restrict__ offA0, const unsigned short* __restrict__ eA0,
    const int* __restrict__ offB0, const unsigned short* __restrict__ eB0,
    const float* __restrict__ bias0, bf16* __restrict__ out0,
    const int* __restrict__ offA1, const unsigned short* __restrict__ eA1,
    const int* __restrict__ offB1, const unsigned short* __restrict__ eB1,
    const float* __restrict__ bias1, bf16* __restrict__ out1)
{
    int tid  = threadIdx.x;
    int gid  = blockIdx.x * 32 + (tid >> 3);   // grid exact: 3125*32 = 100000
    int lidx = tid & 7;
    int half = (gid >= N_NODE);
    int wid  = gid - (half ? N_NODE : 0);
    const int* offA = half ? offA1 : offA0;
    const unsigned short* eA = half ? eA1 : eA0;
    const int* offB = half ? offB1 : offB0;
    const unsigned short* eB = half ? eB1 : eB0;
    const float* bias = half ? bias1 : bias0;
    bf16* out = half ? out1 : out0;

    const unsigned* base = (const unsigned*)m1 + (half ? 32 : 0) + lidx * 4;

    int begA = offA[wid], nA = offA[wid + 1] - begA;
    int begB = offB[wid], nB = offB[wid + 1] - begB;
    float ia = 1.f / (float)max(nA, 1);
    float ib = 1.f / (float)max(nB, 1);

    float s[8] = {0.f,0.f,0.f,0.f,0.f,0.f,0.f,0.f};
    seg_run<64>(nA, eA + begA, ia, base, s);
    seg_run<64>(nB, eB + begB, ib, base + N_NODE * 64, s);

    float h[8];
#pragma unroll
    for (int k = 0; k < 8; k++)
        h[k] = fmaxf(s[k] + bias[lidx * 8 + k], 0.f);
    uint4 v;
    v.x = pk2(h[0], h[1]); v.y = pk2(h[2], h[3]);
    v.z = pk2(h[4], h[5]); v.w = pk2(h[6], h[7]);
    *(uint4*)(out + (size_t)wid * 64 + lidx * 8) = v;
}

// ---------- fused layer-2 gather: 4-lane group per node, 32 feats, f32 out ----------
__global__ __launch_bounds__(256) void k_gather32v2(
    const bf16* __restrict__ m2,
    const int* __restrict__ offA0, const unsigned short* __restrict__ eA0,
    const int* __restrict__ offB0, const unsigned short* __restrict__ eB0,
    const float* __restrict__ bias0, float* __restrict__ out0,
    const int* __restrict__ offA1, const unsigned short* __restrict__ eA1,
    const int* __restrict__ offB1, const unsigned short* __restrict__ eB1,
    const float* __restrict__ bias1, float* __restrict__ out1)
{
    int tid  = threadIdx.x;
    int gid  = blockIdx.x * 64 + (tid >> 2);
    int lidx = tid & 3;
    if (gid >= 2 * N_NODE) return;
    int half = (gid >= N_NODE);
    int wid  = gid - (half ? N_NODE : 0);
    const int* offA = half ? offA1 : offA0;
    const unsigned short* eA = half ? eA1 : eA0;
    const int* offB = half ? offB1 : offB0;
    const unsigned short* eB = half ? eB1 : eB0;
    const float* bias = half ? bias1 : bias0;
    float* out = half ? out1 : out0;

    const unsigned* base = (const unsigned*)m2 + (half ? 16 : 0) + lidx * 4;

    int begA = offA[wid], nA = offA[wid + 1] - begA;
    int begB = offB[wid], nB = offB[wid + 1] - begB;
    float ia = 1.f / (float)max(nA, 1);
    float ib = 1.f / (float)max(nB, 1);

    float s[8] = {0.f,0.f,0.f,0.f,0.f,0.f,0.f,0.f};
    seg_run<32>(nA, eA + begA, ia, base, s);
    seg_run<32>(nB, eB + begB, ib, base + N_NODE * 32, s);

    float* o = out + (size_t)wid * 32 + lidx * 8;
    float4 v0, v1;
    v0.x = s[0] + bias[lidx * 8 + 0];
    v0.y = s[1] + bias[lidx * 8 + 1];
    v0.z = s[2] + bias[lidx * 8 + 2];
    v0.w = s[3] + bias[lidx * 8 + 3];
    v1.x = s[4] + bias[lidx * 8 + 4];
    v1.y = s[5] + bias[lidx * 8 + 5];
    v1.z = s[6] + bias[lidx * 8 + 6];
    v1.w = s[7] + bias[lidx * 8 + 7];
    *(float4*)o = v0;
    *(float4*)(o + 4) = v1;
}

// ---------------- launcher ----------------
extern "C" void kernel_launch(void* const* d_in, const int* in_sizes, int n_in,
                              void* d_out, int out_size, void* d_ws, size_t ws_size,
                              hipStream_t stream)
{
    const float* xd = (const float*)d_in[0];
    const float* xg = (const float*)d_in[1];
    const int* dd_src = (const int*)d_in[2];  const int* dd_dst = (const int*)d_in[3];
    const int* dg_src = (const int*)d_in[4];  const int* dg_dst = (const int*)d_in[5];
    const int* gd_src = (const int*)d_in[6];  const int* gd_dst = (const int*)d_in[7];
    const int* gg_src = (const int*)d_in[8];  const int* gg_dst = (const int*)d_in[9];
    const float* W1dd = (const float*)d_in[10];
    const float* W1dg = (const float*)d_in[11];
    const float* W1gd = (const float*)d_in[12];
    const float* W1gg = (const float*)d_in[13];
    const float* b1d  = (const float*)d_in[14];
    const float* b1g  = (const float*)d_in[15];
    const float* W2dd = (const float*)d_in[16];
    const float* W2dg = (const float*)d_in[17];
    const float* W2gd = (const float*)d_in[18];
    const float* W2gg = (const float*)d_in[19];
    const float* b2d  = (const float*)d_in[20];
    const float* b2g  = (const float*)d_in[21];
    float* out = (float*)d_out;

    // workspace layout (vector-accessed regions 16B-aligned)
    int* gcur     = (int*)d_ws;                        // 512 ints
    int* off      = gcur + 512;                        // 4*(N_NODE+1) = 200004
    unsigned short* edges = (unsigned short*)(off + 4 * (N_NODE + 1));  // 4*NEDGE u16 (4.8 MB)
    bf16* md1     = (bf16*)(edges + (size_t)4 * NEDGE);// [md1|mg1]: 2*50000*128 bf16 (25.6 MB)
    bf16* mg1     = md1 + (size_t)N_NODE * 128;
    bf16* h       = mg1 + (size_t)N_NODE * 128;        // [hd|hg]: 2*50000*64 bf16 (12.8 MB)
    bf16* hd      = h;
    bf16* hg      = h + (size_t)N_NODE * 64;
    bf16* md2     = md1;                               // layer-2 out packed (stride 64 bf16)
    bf16* mg2     = md1 + (size_t)N_NODE * 64;         // B-row i = row (i + N_NODE)
    unsigned* gpart = (unsigned*)h;                    // 512*CAPB uints (12.58 MB) aliases h:
                                                       // dead after csr, before gather64 writes h.
                                                       // (md1 must NOT alias gpart: gemm1 runs || csr.)

    // ---- stage 1: edge partition (standalone, 588 blocks) ----
    hipMemsetAsync(gcur, 0, 512 * sizeof(int), stream);
    k_part<<<4 * NBLK1, 512, 0, stream>>>(
        dd_dst, dd_src, gd_dst, gd_src, dg_dst, dg_src, gg_dst, gg_src, gcur, gpart);

    // ---- stage 2: CSR finalize || layer-1 GEMM (904 blocks, single round) ----
    k_csr_gemm<<<NCSR + 2 * GEMM_GB, 512, 0, stream>>>(
        gpart, gcur, off, edges,
        xd, xg, W1dd, W1dg, W1gd, W1gg, md1, mg1);

    const int* off_dd = off + 0 * (N_NODE + 1);
    const int* off_gd = off + 1 * (N_NODE + 1);
    const int* off_dg = off + 2 * (N_NODE + 1);
    const int* off_gg = off + 3 * (N_NODE + 1);
    const unsigned short* e_dd = edges + (size_t)0 * NEDGE;
    const unsigned short* e_gd = edges + (size_t)1 * NEDGE;
    const unsigned short* e_dg = edges + (size_t)2 * NEDGE;
    const unsigned short* e_gg = edges + (size_t)3 * NEDGE;

    int g64_grid = (2 * N_NODE) / 32;          // 3125 blocks exact
    int g32_grid = (2 * N_NODE + 63) / 64;     // 1563 blocks
    dim3 gemm2_grid((N_NODE + 63) / 64, 2);

    // ---- stage 3: layer-1 gather -> h ----
    k_gather64v5<<<g64_grid, 256, 0, stream>>>(
        md1,
        off_dd, e_dd, off_gd, e_gd, b1d, hd,
        off_dg, e_dg, off_gg, e_gg, b1g, hg);

    // ---- stage 4: layer-2 GEMM (md1 region is dead now) ----
    k_gemm_pair<64, 64, false><<<gemm2_grid, 256, 0, stream>>>(
        hd, hg, W2dd, W2dg, W2gd, W2gg, md2, mg2, N_NODE);

    // ---- stage 5: layer-2 gather -> out ----
    k_gather32v2<<<g32_grid, 256, 0, stream>>>(
        md2,
        off_dd, e_dd, off_gd, e_gd, b2d, out,
        off_dg, e_dg, off_gg, e_gg, b2g, out + (size_t)N_NODE * 32);
}

// Round 13
// 287.684 us; speedup vs baseline: 1.1113x; 1.0585x over previous
//
#include <hip/hip_runtime.h>
#include <hip/hip_bf16.h>

#define N_NODE 50000
#define NEDGE  600000
#define NRANGE 128
#define RSZ    391       // ceil(N_NODE / NRANGE); 128*391 = 50048 >= 50000
#define CAPB   6144      // slot capacity per (rel,range): mean 4688 + ~21 sigma
#define CHUNK  8192
#define NBLK1  74        // ceil(NEDGE / CHUNK); last chunk = 1984 (divisible by 4)
#define GEMM_GB 196      // GEMM blocks per problem; each does 2 row-tiles of 128

typedef __hip_bfloat16 bf16;
typedef __attribute__((ext_vector_type(8))) short short8;
typedef __attribute__((ext_vector_type(4))) float floatx4;

__device__ __forceinline__ short f2s(float f) {
    bf16 t = __float2bfloat16(f);
    return *(short*)&t;
}
__device__ __forceinline__ unsigned pk2(float lo, float hi) {
    return ((unsigned)(unsigned short)f2s(lo)) | (((unsigned)(unsigned short)f2s(hi)) << 16);
}
__device__ __forceinline__ void acc2(float& a, float& b, unsigned w, float m) {
    a += m * __uint_as_float(w << 16);
    b += m * __uint_as_float(w & 0xFFFF0000u);
}
// wave-inclusive scan (64 lanes), Kogge-Stone via shfl_up
__device__ __forceinline__ int wscan(int x, int lane) {
#pragma unroll
    for (int d = 1; d < 64; d <<= 1) {
        int t = __shfl_up(x, d);
        if (lane >= d) x += t;
    }
    return x;
}

// rel 0 = dd (dst=drug), 1 = gd (dst=drug), 2 = dg (dst=gene), 3 = gg (dst=gene)
// key packing: (bucket:7 << 25) | (dst_local:9 << 16) | (src:16)

// ---------- fused launch (512 thr): blocks [0,296) = edge partition, [296,688) = layer-1 GEMM ----------
// 688 blocks <= 1024 residency (4/CU) -> single scheduling round. Shfl scans (1 barrier).
__global__ __launch_bounds__(512) void k_part_gemm(
    const int* __restrict__ d0, const int* __restrict__ s0,
    const int* __restrict__ d1, const int* __restrict__ s1,
    const int* __restrict__ d2, const int* __restrict__ s2,
    const int* __restrict__ d3, const int* __restrict__ s3,
    int* __restrict__ gcur, unsigned* __restrict__ gpart,
    const float* __restrict__ X0, const float* __restrict__ X1,
    const float* __restrict__ Wa0, const float* __restrict__ Wb0,
    const float* __restrict__ Wa1, const float* __restrict__ Wb1,
    bf16* __restrict__ out0, bf16* __restrict__ out1)
{
    __shared__ union {
        struct { unsigned buf[CHUNK]; int hcur[NRANGE]; int delta[NRANGE]; int wsum[2]; } p;
        short wl[4 * 8 * 512];   // 32 KB
    } u;

    int tid = threadIdx.x;
    if (blockIdx.x < 4 * NBLK1) {
        // ---------------- partition path (8192-edge chunks) ----------------
        int bid = blockIdx.x;
        int rel = bid / NBLK1;
        int c   = bid - rel * NBLK1;
        const int* dp = rel == 0 ? d0 : rel == 1 ? d1 : rel == 2 ? d2 : d3;
        const int* sp = rel == 0 ? s0 : rel == 1 ? s1 : rel == 2 ? s2 : s3;
        int e0 = c * CHUNK;
        int e1 = min(e0 + CHUNK, NEDGE);
        int cnt = e1 - e0;                 // 8192 or 1984; both divisible by 4
        const int4* dp4 = (const int4*)(dp + e0);
        const int4* sp4 = (const int4*)(sp + e0);
        int nv = cnt >> 2;

        if (tid < NRANGE) u.p.hcur[tid] = 0;
        __syncthreads();
        // pass 1: bucket counts (int4 loads, LDS atomics)
        for (int i = tid; i < nv; i += 512) {
            int4 d = dp4[i];
            atomicAdd(&u.p.hcur[d.x / RSZ], 1);
            atomicAdd(&u.p.hcur[d.y / RSZ], 1);
            atomicAdd(&u.p.hcur[d.z / RSZ], 1);
            atomicAdd(&u.p.hcur[d.w / RSZ], 1);
        }
        __syncthreads();
        // 128-wide exclusive scan via 2-wave shfl scan (1 barrier)
        int lane = tid & 63, wv6 = tid >> 6;
        int v = (tid < NRANGE) ? u.p.hcur[tid] : 0;
        int inc = wscan(v, lane);
        if (lane == 63 && wv6 < 2) u.p.wsum[wv6] = inc;
        __syncthreads();
        if (tid < NRANGE) {
            int incl  = inc + ((wv6 == 1) ? u.p.wsum[0] : 0);
            int start = incl - v;
            int bg    = rel * NRANGE + tid;
            int resv  = atomicAdd(&gcur[bg], v);
            u.p.delta[tid] = bg * CAPB + resv - start;
            u.p.hcur[tid]  = start;
        }
        __syncthreads();
        // pass 2: fill buf bucketed
        for (int i = tid; i < nv; i += 512) {
            int4 d = dp4[i];
            int4 s = sp4[i];
#define PUT(dd, ss) { int b = (dd) / RSZ; int p = atomicAdd(&u.p.hcur[b], 1); \
                      u.p.buf[p] = ((unsigned)b << 25) | ((unsigned)((dd) - b * RSZ) << 16) | (unsigned)(ss); }
            PUT(d.x, s.x) PUT(d.y, s.y) PUT(d.z, s.z) PUT(d.w, s.w)
#undef PUT
        }
        __syncthreads();
        // pass 3: scatter to global slots
        for (int i = tid * 4; i < cnt; i += 2048) {
            uint4 kb = *(const uint4*)&u.p.buf[i];
            gpart[u.p.delta[kb.x >> 25] + i + 0] = kb.x;
            gpart[u.p.delta[kb.y >> 25] + i + 1] = kb.y;
            gpart[u.p.delta[kb.z >> 25] + i + 2] = kb.z;
            gpart[u.p.delta[kb.w >> 25] + i + 3] = kb.w;
        }
    } else {
        // ---------------- layer-1 GEMM path: 2 row-tiles of 128 per block, 8 waves ----------------
        constexpr int NB = 8, KC = 4, NH = 64;
        int bid2 = blockIdx.x - 4 * NBLK1;         // 0..391
        int sel  = bid2 >= GEMM_GB;
        int bx   = sel ? bid2 - GEMM_GB : bid2;
        const float* X  = sel ? X1 : X0;
        const float* Wa = sel ? Wa1 : Wa0;
        const float* Wb = sel ? Wb1 : Wb0;
        bf16*       outp = sel ? out1 : out0;

        for (int i = tid; i < KC * NB * 512; i += 512) {
            int j  = i & 7;
            int n  = (i >> 3) & 15;
            int q  = (i >> 7) & 3;
            int nb = (i >> 9) & (NB - 1);
            int kc = i >> 12;
            int k  = kc * 32 + q * 8 + j;
            int c  = nb * 16 + n;
            float w = (c < NH) ? Wa[k * NH + c] : Wb[k * NH + (c - NH)];
            u.wl[i] = f2s(w);
        }
        __syncthreads();

        int lane = tid & 63, wv = tid >> 6;        // wv in [0,8)
        int q = lane >> 4, lidx = lane & 15;

#pragma unroll
        for (int t = 0; t < 2; t++) {
            int tile = bx * 2 + t;
            if (tile * 128 >= N_NODE) break;       // dead tail tile (tile 391)
            int row0 = tile * 128 + wv * 16;
            int rowA = min(row0 + lidx, N_NODE - 1);

            floatx4 acc[NB];
#pragma unroll
            for (int nb = 0; nb < NB; nb++) acc[nb] = (floatx4){0.f, 0.f, 0.f, 0.f};

#pragma unroll
            for (int kc = 0; kc < KC; kc++) {
                const float* Xf = X + (size_t)rowA * 128 + kc * 32 + q * 8;
                float4 f0 = *(const float4*)Xf;
                float4 f1 = *(const float4*)(Xf + 4);
                short8 a;
                a[0] = f2s(f0.x); a[1] = f2s(f0.y); a[2] = f2s(f0.z); a[3] = f2s(f0.w);
                a[4] = f2s(f1.x); a[5] = f2s(f1.y); a[6] = f2s(f1.z); a[7] = f2s(f1.w);
#pragma unroll
                for (int nb = 0; nb < NB; nb++) {
                    short8 b = *(const short8*)&u.wl[((kc * NB + nb) * 64 + lane) * 8];
                    acc[nb] = __builtin_amdgcn_mfma_f32_16x16x32_bf16(a, b, acc[nb], 0, 0, 0);
                }
            }
#pragma unroll
            for (int nb = 0; nb < NB; nb++) {
#pragma unroll
                for (int r = 0; r < 4; r++) {
                    int row = row0 + q * 4 + r;
                    if (row < N_NODE)
                        outp[(size_t)row * 128 + nb * 16 + lidx] = __float2bfloat16(acc[nb][r]);
                }
            }
        }
    }
}

// ---------- per (rel,range) block -> final CSR (512 thr, uint4 loads, shfl scans) ----------
__global__ __launch_bounds__(512) void k_csr(
    const unsigned* __restrict__ gpart, const int* __restrict__ gcnt,
    int* __restrict__ off, unsigned short* __restrict__ edges)
{
    __shared__ unsigned short stg[CAPB];   // first: 16B-aligned
    __shared__ int cur[RSZ];
    __shared__ int wsum[8];
    int bid = blockIdx.x;
    int rel = bid >> 7, r = bid & (NRANGE - 1);
    int tid = threadIdx.x;
    int lane = tid & 63, wv = tid >> 6;
    int range0 = r * RSZ;
    int RS = min(RSZ, N_NODE - range0);
    if (RS < 0) RS = 0;
    int count = gcnt[bid];
    const uint4* gp4 = (const uint4*)(gpart + (size_t)bid * CAPB);
    const unsigned* gp = gpart + (size_t)bid * CAPB;
    int count4 = count & ~3;

    // base = sum of gcnt[rel*128 + i] for i < r : masked 2-wave reduction (1 barrier)
    int vb = (tid < r) ? gcnt[rel * NRANGE + tid] : 0;   // tid<r implies tid<128
#pragma unroll
    for (int d = 32; d; d >>= 1) vb += __shfl_xor(vb, d);
    if (lane == 0 && wv < 2) wsum[wv] = vb;
    for (int i = tid; i < RSZ; i += 512) cur[i] = 0;
    __syncthreads();
    int base = wsum[0] + wsum[1];

    // hist (uint4)
    for (int i = tid * 4; i < count4; i += 2048) {
        uint4 g = gp4[i >> 2];
        atomicAdd(&cur[(g.x >> 16) & 0x1FF], 1);
        atomicAdd(&cur[(g.y >> 16) & 0x1FF], 1);
        atomicAdd(&cur[(g.z >> 16) & 0x1FF], 1);
        atomicAdd(&cur[(g.w >> 16) & 0x1FF], 1);
    }
    if (tid < (count & 3))
        atomicAdd(&cur[(gp[count4 + tid] >> 16) & 0x1FF], 1);
    __syncthreads();

    // 391-wide exclusive scan via 8-wave shfl scan (2 barriers)
    int x = (tid < RSZ) ? cur[tid] : 0;
    int inc = wscan(x, lane);
    if (lane == 63) wsum[wv] = inc;
    __syncthreads();
    int pre = 0;
#pragma unroll
    for (int w = 0; w < 7; w++) pre += (w < wv) ? wsum[w] : 0;
    int excl = inc + pre - x;
    if (tid < RSZ) cur[tid] = excl;
    __syncthreads();

    if (tid < RS)
        off[rel * (N_NODE + 1) + range0 + tid] = base + cur[tid];
    if (r == NRANGE - 1 && tid == 0) off[rel * (N_NODE + 1) + N_NODE] = NEDGE;
    // no barrier needed: off written from cur[tid] (own slot), scatter uses atomics on cur

    // scatter to stg (uint4)
    for (int i = tid * 4; i < count4; i += 2048) {
        uint4 g = gp4[i >> 2];
#define SCAT(gg) { int p = atomicAdd(&cur[((gg) >> 16) & 0x1FF], 1); stg[p] = (unsigned short)((gg) & 0xFFFFu); }
        SCAT(g.x) SCAT(g.y) SCAT(g.z) SCAT(g.w)
#undef SCAT
    }
    if (tid < (count & 3)) {
        unsigned g = gp[count4 + tid];
        int p = atomicAdd(&cur[(g >> 16) & 0x1FF], 1);
        stg[p] = (unsigned short)(g & 0xFFFFu);
    }
    __syncthreads();
    for (int i = tid; i < count; i += 512)
        edges[(size_t)rel * NEDGE + base + i] = stg[i];
}

// ---------- MFMA dual-weight GEMM pair (layer 2): out(bf16) = X @ [Wa | Wb] ----------
template <int K, int NOUT, bool AFP32>
__global__ __launch_bounds__(256) void k_gemm_pair(
    const void* __restrict__ X0, const void* __restrict__ X1,
    const float* __restrict__ Wa0, const float* __restrict__ Wb0,
    const float* __restrict__ Wa1, const float* __restrict__ Wb1,
    bf16* __restrict__ out0, bf16* __restrict__ out1, int M)
{
    constexpr int NB  = NOUT / 16;
    constexpr int KC  = K / 32;
    constexpr int NH  = NOUT / 2;
    constexpr int NBL = (NB == 8) ? 3 : 2;
    __shared__ short Wl[KC * NB * 512];

    int sel = blockIdx.y;
    const void*  X  = sel ? X1 : X0;
    const float* Wa = sel ? Wa1 : Wa0;
    const float* Wb = sel ? Wb1 : Wb0;
    bf16*        out = sel ? out1 : out0;

    int tid = threadIdx.x;
    for (int i = tid; i < KC * NB * 512; i += 256) {
        int j  = i & 7;
        int n  = (i >> 3) & 15;
        int q  = (i >> 7) & 3;
        int nb = (i >> 9) & (NB - 1);
        int kc = i >> (9 + NBL);
        int k  = kc * 32 + q * 8 + j;
        int c  = nb * 16 + n;
        float w = (c < NH) ? Wa[k * NH + c] : Wb[k * NH + (c - NH)];
        Wl[i] = f2s(w);
    }
    __syncthreads();

    int lane = tid & 63, wv = tid >> 6;
    int q = lane >> 4, lidx = lane & 15;
    int row0 = blockIdx.x * 64 + wv * 16;
    int rowA = min(row0 + lidx, M - 1);

    floatx4 acc[NB];
#pragma unroll
    for (int nb = 0; nb < NB; nb++) acc[nb] = (floatx4){0.f, 0.f, 0.f, 0.f};

#pragma unroll
    for (int kc = 0; kc < KC; kc++) {
        short8 a;
        if constexpr (AFP32) {
            const float* Xf = (const float*)X + (size_t)rowA * K + kc * 32 + q * 8;
            float4 f0 = *(const float4*)Xf;
            float4 f1 = *(const float4*)(Xf + 4);
            a[0] = f2s(f0.x); a[1] = f2s(f0.y); a[2] = f2s(f0.z); a[3] = f2s(f0.w);
            a[4] = f2s(f1.x); a[5] = f2s(f1.y); a[6] = f2s(f1.z); a[7] = f2s(f1.w);
        } else {
            a = *(const short8*)((const short*)X + (size_t)rowA * K + kc * 32 + q * 8);
        }
#pragma unroll
        for (int nb = 0; nb < NB; nb++) {
            short8 b = *(const short8*)&Wl[((kc * NB + nb) * 64 + lane) * 8];
            acc[nb] = __builtin_amdgcn_mfma_f32_16x16x32_bf16(a, b, acc[nb], 0, 0, 0);
        }
    }
#pragma unroll
    for (int nb = 0; nb < NB; nb++) {
#pragma unroll
        for (int r = 0; r < 4; r++) {
            int row = row0 + q * 4 + r;
            if (row < M)
                out[(size_t)row * NOUT + nb * 16 + lidx] = __float2bfloat16(acc[nb][r]);
        }
    }
}

// ---------- group-per-node segment accumulate (round-2 proven structure, u16 edges) ----------
template<int ROWU>
__device__ __forceinline__ void seg_run(
    int n, const unsigned short* __restrict__ ep, float sc,
    const unsigned* __restrict__ base, float* s)
{
    int nfull = n & ~3;
    for (int i = 0; i < nfull; i += 4) {
        int e0 = ep[i + 0];
        int e1 = ep[i + 1];
        int e2 = ep[i + 2];
        int e3 = ep[i + 3];
        uint4 w0 = *(const uint4*)(base + e0 * ROWU);
        uint4 w1 = *(const uint4*)(base + e1 * ROWU);
        uint4 w2 = *(const uint4*)(base + e2 * ROWU);
        uint4 w3 = *(const uint4*)(base + e3 * ROWU);
        acc2(s[0], s[1], w0.x, sc); acc2(s[2], s[3], w0.y, sc);
        acc2(s[4], s[5], w0.z, sc); acc2(s[6], s[7], w0.w, sc);
        acc2(s[0], s[1], w1.x, sc); acc2(s[2], s[3], w1.y, sc);
        acc2(s[4], s[5], w1.z, sc); acc2(s[6], s[7], w1.w, sc);
        acc2(s[0], s[1], w2.x, sc); acc2(s[2], s[3], w2.y, sc);
        acc2(s[4], s[5], w2.z, sc); acc2(s[6], s[7], w2.w, sc);
        acc2(s[0], s[1], w3.x, sc); acc2(s[2], s[3], w3.y, sc);
        acc2(s[4], s[5], w3.z, sc); acc2(s[6], s[7], w3.w, sc);
    }
    for (int i = nfull; i < n; i++) {
        int e = ep[i];
        uint4 w = *(const uint4*)(base + e * ROWU);
        acc2(s[0], s[1], w.x, sc); acc2(s[2], s[3], w.y, sc);
        acc2(s[4], s[5], w.z, sc); acc2(s[6], s[7], w.w, sc);
    }
}

// ---------- fused layer-1 gather: 8-lane group per node, 64 feats ----------
__global__ __launch_bounds__(256) void k_gather64v5(
    const bf16* __restrict__ m1,
    const int* __restrict__ offA0, const unsigned short* __restrict__ eA0,
    const int* __restrict__ offB0, const unsigned short* __restrict__ eB0,
    const float* __restrict__ bias0, bf16* __restrict__ out0,
    const int* __restrict__ offA1, const unsigned short* __restrict__ eA1,
    const int* __restrict__ offB1, const unsigned short* __restrict__ eB1,
    const float* __restrict__ bias1, bf16* __restrict__ out1)
{
    int tid  = threadIdx.x;
    int gid  = blockIdx.x * 32 + (tid >> 3);   // grid exact: 3125*32 = 100000
    int lidx = tid & 7;
    int half = (gid >= N_NODE);
    int wid  = gid - (half ? N_NODE : 0);
    const int* offA = half ? offA1 : offA0;
    const unsigned short* eA = half ? eA1 : eA0;
    const int* offB = half ? offB1 : offB0;
    const unsigned short* eB = half ? eB1 : eB0;
    const float* bias = half ? bias1 : bias0;
    bf16* out = half ? out1 : out0;

    const unsigned* base = (const unsigned*)m1 + (half ? 32 : 0) + lidx * 4;

    int begA = offA[wid], nA = offA[wid + 1] - begA;
    int begB = offB[wid], nB = offB[wid + 1] - begB;
    float ia = 1.f / (float)max(nA, 1);
    float ib = 1.f / (float)max(nB, 1);

    float s[8] = {0.f,0.f,0.f,0.f,0.f,0.f,0.f,0.f};
    seg_run<64>(nA, eA + begA, ia, base, s);
    seg_run<64>(nB, eB + begB, ib, base + N_NODE * 64, s);

    float h[8];
#pragma unroll
    for (int k = 0; k < 8; k++)
        h[k] = fmaxf(s[k] + bias[lidx * 8 + k], 0.f);
    uint4 v;
    v.x = pk2(h[0], h[1]); v.y = pk2(h[2], h[3]);
    v.z = pk2(h[4], h[5]); v.w = pk2(h[6], h[7]);
    *(uint4*)(out + (size_t)wid * 64 + lidx * 8) = v;
}

// ---------- fused layer-2 gather: 4-lane group per node, 32 feats, f32 out ----------
__global__ __launch_bounds__(256) void k_gather32v2(
    const bf16* __restrict__ m2,
    const int* __restrict__ offA0, const unsigned short* __restrict__ eA0,
    const int* __restrict__ offB0, const unsigned short* __restrict__ eB0,
    const float* __restrict__ bias0, float* __restrict__ out0,
    const int* __restrict__ offA1, const unsigned short* __restrict__ eA1,
    const int* __restrict__ offB1, const unsigned short* __restrict__ eB1,
    const float* __restrict__ bias1, float* __restrict__ out1)
{
    int tid  = threadIdx.x;
    int gid  = blockIdx.x * 64 + (tid >> 2);
    int lidx = tid & 3;
    if (gid >= 2 * N_NODE) return;
    int half = (gid >= N_NODE);
    int wid  = gid - (half ? N_NODE : 0);
    const int* offA = half ? offA1 : offA0;
    const unsigned short* eA = half ? eA1 : eA0;
    const int* offB = half ? offB1 : offB0;
    const unsigned short* eB = half ? eB1 : eB0;
    const float* bias = half ? bias1 : bias0;
    float* out = half ? out1 : out0;

    const unsigned* base = (const unsigned*)m2 + (half ? 16 : 0) + lidx * 4;

    int begA = offA[wid], nA = offA[wid + 1] - begA;
    int begB = offB[wid], nB = offB[wid + 1] - begB;
    float ia = 1.f / (float)max(nA, 1);
    float ib = 1.f / (float)max(nB, 1);

    float s[8] = {0.f,0.f,0.f,0.f,0.f,0.f,0.f,0.f};
    seg_run<32>(nA, eA + begA, ia, base, s);
    seg_run<32>(nB, eB + begB, ib, base + N_NODE * 32, s);

    float* o = out + (size_t)wid * 32 + lidx * 8;
    float4 v0, v1;
    v0.x = s[0] + bias[lidx * 8 + 0];
    v0.y = s[1] + bias[lidx * 8 + 1];
    v0.z = s[2] + bias[lidx * 8 + 2];
    v0.w = s[3] + bias[lidx * 8 + 3];
    v1.x = s[4] + bias[lidx * 8 + 4];
    v1.y = s[5] + bias[lidx * 8 + 5];
    v1.z = s[6] + bias[lidx * 8 + 6];
    v1.w = s[7] + bias[lidx * 8 + 7];
    *(float4*)o = v0;
    *(float4*)(o + 4) = v1;
}

// ---------------- launcher ----------------
extern "C" void kernel_launch(void* const* d_in, const int* in_sizes, int n_in,
                              void* d_out, int out_size, void* d_ws, size_t ws_size,
                              hipStream_t stream)
{
    const float* xd = (const float*)d_in[0];
    const float* xg = (const float*)d_in[1];
    const int* dd_src = (const int*)d_in[2];  const int* dd_dst = (const int*)d_in[3];
    const int* dg_src = (const int*)d_in[4];  const int* dg_dst = (const int*)d_in[5];
    const int* gd_src = (const int*)d_in[6];  const int* gd_dst = (const int*)d_in[7];
    const int* gg_src = (const int*)d_in[8];  const int* gg_dst = (const int*)d_in[9];
    const float* W1dd = (const float*)d_in[10];
    const float* W1dg = (const float*)d_in[11];
    const float* W1gd = (const float*)d_in[12];
    const float* W1gg = (const float*)d_in[13];
    const float* b1d  = (const float*)d_in[14];
    const float* b1g  = (const float*)d_in[15];
    const float* W2dd = (const float*)d_in[16];
    const float* W2dg = (const float*)d_in[17];
    const float* W2gd = (const float*)d_in[18];
    const float* W2gg = (const float*)d_in[19];
    const float* b2d  = (const float*)d_in[20];
    const float* b2g  = (const float*)d_in[21];
    float* out = (float*)d_out;

    // workspace layout (vector-accessed regions 16B-aligned)
    int* gcur     = (int*)d_ws;                        // 512 ints
    int* off      = gcur + 512;                        // 4*(N_NODE+1) = 200004
    unsigned short* edges = (unsigned short*)(off + 4 * (N_NODE + 1));  // 4*NEDGE u16 (4.8 MB)
    bf16* md1     = (bf16*)(edges + (size_t)4 * NEDGE);// [md1|mg1]: 2*50000*128 bf16 (25.6 MB)
    bf16* mg1     = md1 + (size_t)N_NODE * 128;
    bf16* h       = mg1 + (size_t)N_NODE * 128;        // [hd|hg]: 2*50000*64 bf16 (12.8 MB)
    bf16* hd      = h;
    bf16* hg      = h + (size_t)N_NODE * 64;
    bf16* md2     = md1;                               // layer-2 out packed (stride 64 bf16)
    bf16* mg2     = md1 + (size_t)N_NODE * 64;         // B-row i = row (i + N_NODE)
    unsigned* gpart = (unsigned*)h;                    // 512*CAPB uints (12.58 MB) aliases h:
                                                       // dead after k_csr, before gather64 writes h.
                                                       // (md1 must NOT alias gpart: GEMM runs || part.)

    // ---- stage 1: edge partition || layer-1 GEMM (688 blocks -> single scheduling round) ----
    hipMemsetAsync(gcur, 0, 512 * sizeof(int), stream);
    k_part_gemm<<<4 * NBLK1 + 2 * GEMM_GB, 512, 0, stream>>>(
        dd_dst, dd_src, gd_dst, gd_src, dg_dst, dg_src, gg_dst, gg_src, gcur, gpart,
        xd, xg, W1dd, W1dg, W1gd, W1gg, md1, mg1);

    // ---- stage 2: CSR finalize ----
    k_csr<<<512, 512, 0, stream>>>(gpart, gcur, off, edges);

    const int* off_dd = off + 0 * (N_NODE + 1);
    const int* off_gd = off + 1 * (N_NODE + 1);
    const int* off_dg = off + 2 * (N_NODE + 1);
    const int* off_gg = off + 3 * (N_NODE + 1);
    const unsigned short* e_dd = edges + (size_t)0 * NEDGE;
    const unsigned short* e_gd = edges + (size_t)1 * NEDGE;
    const unsigned short* e_dg = edges + (size_t)2 * NEDGE;
    const unsigned short* e_gg = edges + (size_t)3 * NEDGE;

    int g64_grid = (2 * N_NODE) / 32;          // 3125 blocks exact
    int g32_grid = (2 * N_NODE + 63) / 64;     // 1563 blocks
    dim3 gemm2_grid((N_NODE + 63) / 64, 2);

    // ---- stage 3: layer-1 gather -> h ----
    k_gather64v5<<<g64_grid, 256, 0, stream>>>(
        md1,
        off_dd, e_dd, off_gd, e_gd, b1d, hd,
        off_dg, e_dg, off_gg, e_gg, b1g, hg);

    // ---- stage 4: layer-2 GEMM (md1 region is dead now) ----
    k_gemm_pair<64, 64, false><<<gemm2_grid, 256, 0, stream>>>(
        hd, hg, W2dd, W2dg, W2gd, W2gg, md2, mg2, N_NODE);

    // ---- stage 5: layer-2 gather -> out ----
    k_gather32v2<<<g32_grid, 256, 0, stream>>>(
        md2,
        off_dd, e_dd, off_gd, e_gd, b2d, out,
        off_dg, e_dg, off_gg, e_gg, b2g, out + (size_t)N_NODE * 32);
}